// Round 7
// baseline (6326.620 us; speedup 1.0000x reference)
//
#include <hip/hip_runtime.h>
#include <math.h>

// Problem dims
#define T_ 128
#define B_ 512
#define N_ 256
#define M_ 512
#define G_ 2048   // 4*M
#define NBLK 256  // 8 groups x 32 blocks, 1 block/CU, 512 threads = 8 waves/CU
#define GSZ 32    // blocks per group
#define KC_ 24    // K chunks of 32 (768 total: 256 x-tilde + 512 h)

typedef unsigned long long ull;
typedef __attribute__((ext_vector_type(8))) short short8v;
typedef __attribute__((ext_vector_type(4))) float float4v;

// ---------------------------------------------------------------------------
// Device-coherent access, relaxed: cross-XCD safe
// ---------------------------------------------------------------------------
__device__ __forceinline__ float ld_dev(const float* p) {
    return __hip_atomic_load(const_cast<float*>(p), __ATOMIC_RELAXED,
                             __HIP_MEMORY_SCOPE_AGENT);
}
__device__ __forceinline__ void st_dev(float* p, float v) {
    __hip_atomic_store(p, v, __ATOMIC_RELAXED, __HIP_MEMORY_SCOPE_AGENT);
}
__device__ __forceinline__ ull ld_dev64(const ull* p) {
    return __hip_atomic_load(const_cast<ull*>(p), __ATOMIC_RELAXED,
                             __HIP_MEMORY_SCOPE_AGENT);
}
__device__ __forceinline__ void st_dev64(ull* p, ull v) {
    __hip_atomic_store(p, v, __ATOMIC_RELAXED, __HIP_MEMORY_SCOPE_AGENT);
}

// Fast transcendentals (abs err ~1e-6, threshold 1e-3)
__device__ __forceinline__ float fast_tanh(float x) {
    float e = __expf(2.f * x);
    return 1.f - __fdividef(2.f, e + 1.f);
}
__device__ __forceinline__ float fast_sig(float x) {
    return __fdividef(1.f, 1.f + __expf(-x));
}

// bf16 helpers (RNE)
__device__ __forceinline__ unsigned short bf16_rne(float f) {
    unsigned u = __float_as_uint(f);
    return (unsigned short)((u + 0x7FFFu + ((u >> 16) & 1u)) >> 16);
}
__device__ __forceinline__ float bf16_tof(unsigned short h) {
    return __uint_as_float(((unsigned)h) << 16);
}
__device__ __forceinline__ ull pack4(const unsigned short* s) {
    return (ull)s[0] | ((ull)s[1] << 16) | ((ull)s[2] << 32) | ((ull)s[3] << 48);
}

// ---------------------------------------------------------------------------
// Group barrier: 32 blocks, relaxed ticket, no L2 flush.
// ---------------------------------------------------------------------------
__device__ __forceinline__ void group_bar(int* gbar, int goal) {
    __syncthreads();
    if (threadIdx.x == 0) {
        asm volatile("s_waitcnt vmcnt(0)" ::: "memory");
        __hip_atomic_fetch_add(gbar, 1, __ATOMIC_RELAXED,
                               __HIP_MEMORY_SCOPE_AGENT);
        while (__hip_atomic_load(gbar, __ATOMIC_RELAXED,
                                 __HIP_MEMORY_SCOPE_AGENT) < goal) {
            __builtin_amdgcn_s_sleep(1);
        }
    }
    __syncthreads();
}

// ---------------------------------------------------------------------------
// Prep: fused bias bg[4m+g] = b_ih[g*512+m] + b_hh[g*512+m]
// ---------------------------------------------------------------------------
__global__ __launch_bounds__(256) void prep_bg(
    const float* __restrict__ bih, const float* __restrict__ bhh,
    float* __restrict__ bg)
{
    int rp = blockIdx.x * 256 + threadIdx.x;
    if (rp < 2048) {
        int m = rp >> 2, g = rp & 3;
        int row = g * 512 + m;
        bg[rp] = bih[row] + bhh[row];
    }
}

// ---------------------------------------------------------------------------
// Prep: Wt fragment-tiled bf16 hi/lo planes (kc 0..7 = x part, 8..23 = h).
// ---------------------------------------------------------------------------
__global__ __launch_bounds__(256) void prep_wt(
    const float* __restrict__ Wih, const float* __restrict__ Whh,
    uint4* __restrict__ Wt_hi, uint4* __restrict__ Wt_lo)
{
    int uid = blockIdx.x * 256 + threadIdx.x;   // < 196608
    int ct = uid / (KC_ * 64);
    int rem = uid % (KC_ * 64);
    int kc = rem >> 6, lane = rem & 63;
    int col = ct * 16 + (lane & 15);
    int m = col >> 2, gi = col & 3;
    int grow = gi * 512 + m;
    int quad = lane >> 4;
    union { unsigned short s[8]; uint4 v; } hi, lo;
#pragma unroll
    for (int j = 0; j < 8; j++) {
        int k = kc * 32 + quad * 8 + j;
        float v = (k < 256) ? Wih[(size_t)grow * 256 + k]
                            : Whh[(size_t)grow * 512 + (k - 256)];
        hi.s[j] = bf16_rne(v);
        lo.s[j] = bf16_rne(v - bf16_tof(hi.s[j]));
    }
    Wt_hi[uid] = hi.v;
    Wt_lo[uid] = lo.v;
}

// We_p[q][s][j] = We_w[s][q*4+j]   (f32 — bf16 variant regressed, round 6)
__global__ __launch_bounds__(256) void prep_wep(
    const float* __restrict__ We_w, float* __restrict__ We_p)
{
    int idx = blockIdx.x * 256 + threadIdx.x;   // < 131072
    int q = idx >> 9, rest = idx & 511, s = rest >> 2, j = rest & 3;
    We_p[idx] = We_w[s * 1024 + q * 4 + j];
}

// ---------------------------------------------------------------------------
// Precompute (Ue_x + Ue_b) * 2, packed bf16 s-pairs.
// ---------------------------------------------------------------------------
__global__ __launch_bounds__(256) void ue_pre(
    const float* __restrict__ x, const float* __restrict__ Ue_w,
    const float* __restrict__ Ue_b, unsigned* __restrict__ ue_pk)
{
    const int b = blockIdx.y;
    const int s0 = blockIdx.x * 32;
    const int n = threadIdx.x;
    __shared__ float xs[32][256];
    __shared__ float uws[32][32];

    float acc[32];
#pragma unroll
    for (int i = 0; i < 32; i++) acc[i] = 0.f;

#pragma unroll 1
    for (int tc = 0; tc < 4; tc++) {
        __syncthreads();
#pragma unroll
        for (int tt = 0; tt < 32; tt++)
            xs[tt][n] = x[(size_t)(tc * 32 + tt) * (B_ * N_) + b * N_ + n];
#pragma unroll
        for (int q = 0; q < 4; q++) {
            int e = q * 256 + n;
            int s = e >> 5, tt = e & 31;
            uws[s][tt] = Ue_w[(s0 + s) * T_ + tc * 32 + tt];
        }
        __syncthreads();
        float xr[32];
#pragma unroll
        for (int tt = 0; tt < 32; tt++) xr[tt] = xs[tt][n];
#pragma unroll
        for (int s = 0; s < 32; s++) {
            float a = acc[s];
#pragma unroll
            for (int tt = 0; tt < 32; tt++) a += xr[tt] * uws[s][tt];
            acc[s] = a;
        }
    }
#pragma unroll
    for (int i = 0; i < 16; i++) {
        float v0 = (acc[2 * i] + Ue_b[s0 + 2 * i]) * 2.0f;
        float v1 = (acc[2 * i + 1] + Ue_b[s0 + 2 * i + 1]) * 2.0f;
        unsigned pk = (unsigned)bf16_rne(v0) | ((unsigned)bf16_rne(v1) << 16);
        ue_pk[((size_t)b * 64 + (s0 >> 1) + i) * 256 + n] = pk;
    }
}

// ---------------------------------------------------------------------------
// Persistent scan, round-7 restructure (math bit-identical to round 2):
//  - h-region At(t+1) emitted at END of C(t) from LDS-staged cell outputs
//    (round-3 "tail" mapping, correctness-validated there). Parity double
//    buffer for the h-region; x-region stays single-buffered.
//  - The h-part gates GEMM (16 kc, 2/3 of Part C) moves into the A-phase,
//    interleaved 4-we-iterations-per-kc with the we-GEMM (rolled, 1-ahead —
//    same pacing discipline as the frozen R2 loop). Its At latency hides
//    under we/attention VALU; C-phase shrinks to x-GEMM (8 kc) + cell.
//  - We stream f32 (bf16 regressed: Part A is VALU-bound, round 6).
// ---------------------------------------------------------------------------
__global__ __launch_bounds__(512, 1) void scan_persist(
    const float* __restrict__ x, const float* __restrict__ h0,
    const float* __restrict__ We_p, const float* __restrict__ We_b,
    const float* __restrict__ ve_w, const unsigned* __restrict__ ue_pk,
    const short8v* __restrict__ Wt_hi, const short8v* __restrict__ Wt_lo,
    const float* __restrict__ bg,
    float* __restrict__ cbuf, float* __restrict__ hseq,
    ull* __restrict__ Atx_hi, ull* __restrict__ Atx_lo,
    ull* __restrict__ Ath_hi0, ull* __restrict__ Ath_lo0,
    ull* __restrict__ Ath_hi1, ull* __restrict__ Ath_lo1,
    int* bar)
{
    const int tid = threadIdx.x;
    const int blk = blockIdx.x;
    const int g = blk >> 5;          // group 0..7
    const int sg = blk & 31;         // slot in group
    int* gbar = bar + g * 32;

    __shared__ __align__(16) float hcA[1024];
    __shared__ __align__(16) float hcB[1024];
    __shared__ float wepartA[512];
    __shared__ float wepartB[512];
    __shared__ __align__(16) float wv[2][256];   // [half][s*2+{2*we, 2*ve}]
    __shared__ float red[16];
    __shared__ float xs[2][256];
    __shared__ float gates_s[64][65];
    __shared__ float hn_s[64][17];               // cell h staging for h-emit

    // part A ids
    const int bA = g * 64 + sg * 2;
    const int bB = bA + 1;
    const int s_ = tid & 127;
    const int qr = tid >> 7;
    const int half = tid >> 8;       // batch half (wave-uniform)
    const int tt = tid & 255;        // n
    // part C ids
    const int lane = tid & 63;
    const int w = tid >> 6;          // wave 0..7
    const int rtC = g * 4 + (w & 3);
    const int ctA = sg * 4 + (w >> 2) * 2;
    const int ctB = ctA + 1;
    const int quad = lane >> 4;
    // cell ids (loop-invariant)
    const int mi_c = tid & 15;
    const int b_l0 = tid >> 4;                   // 0..31
    const int cidx0 = (g * 64 + b_l0) * M_ + sg * 16 + mi_c;
    const int cidx1 = cidx0 + 32 * M_;

    if (tid < 128) {
        float v = 2.0f * ve_w[tid];  // pre-doubled: e -= (2*ve) * rcp(E+1)
        wv[0][tid * 2 + 1] = v;
        wv[1][tid * 2 + 1] = v;
    }

    // loop-invariant fused biases for this thread's cells
    const float bgi = bg[sg * 64 + mi_c * 4 + 0];
    const float bgf = bg[sg * 64 + mi_c * 4 + 1];
    const float bgc = bg[sg * 64 + mi_c * 4 + 2];
    const float bgo = bg[sg * 64 + mi_c * 4 + 3];

    // ---- one-time: load this thread's ue slice (all 128 s) into VGPRs ----
    unsigned ureg[64];
    {
        const unsigned* up = ue_pk + ((size_t)(bA + half) * 64) * 256 + tt;
#pragma unroll
        for (int i = 0; i < 64; i++) ureg[i] = up[(size_t)i * 256];
    }

    // ---- prologue: emit h-At(0) (parity 0) from h0 ----
    if (tid < 128) {
        int rt_l = tid >> 5;
        int q = (tid >> 4) & 1;
        int b_lo = tid & 15;
        int b_local = rt_l * 16 + b_lo;
        float v[8];
#pragma unroll
        for (int j = 0; j < 8; j++)
            v[j] = h0[(size_t)(g * 64 + b_local) * M_ + sg * 16 + q * 8 + j];
        unsigned short hi[8], lo[8];
#pragma unroll
        for (int j = 0; j < 8; j++) {
            hi[j] = bf16_rne(v[j]);
            lo[j] = bf16_rne(v[j] - bf16_tof(hi[j]));
        }
        int kh = sg >> 1;
        int ln = (2 * (sg & 1) + q) * 16 + b_lo;
        size_t uidx = ((size_t)((g * 4 + rt_l) * 16 + kh) * 64 + ln) * 2;
        st_dev64(Ath_hi0 + uidx,     pack4(hi));
        st_dev64(Ath_hi0 + uidx + 1, pack4(hi + 4));
        st_dev64(Ath_lo0 + uidx,     pack4(lo));
        st_dev64(Ath_lo0 + uidx + 1, pack4(lo + 4));
    }
    int bgoal = GSZ;
    group_bar(gbar, bgoal); bgoal += GSZ;

#pragma unroll 1
    for (int t = 0; t < T_; t++) {
        const float* hprev = t ? (hseq + (size_t)(t - 1) * (B_ * M_)) : h0;
        const int par = t & 1;
        const ull* Hh = par ? Ath_hi1 : Ath_hi0;
        const ull* Hl = par ? Ath_lo1 : Ath_lo0;
        ull* nHh = par ? Ath_hi0 : Ath_hi1;
        ull* nHl = par ? Ath_lo0 : Ath_lo1;

        float4v acc0 = {0.f, 0.f, 0.f, 0.f};
        float4v acc1 = {0.f, 0.f, 0.f, 0.f};
        float cold0, cold1;

        // ---------------- Part A (+ fused h-part gates GEMM) ----------------
        {
            hcA[tid]       = ld_dev(hprev + bA * M_ + tid);
            hcA[512 + tid] = ld_dev(cbuf + bA * M_ + tid);
            hcB[tid]       = ld_dev(hprev + bB * M_ + tid);
            hcB[512 + tid] = ld_dev(cbuf + bB * M_ + tid);
            // block-private cell state: safe to read any time after bar2(t-1)
            cold0 = ld_dev(&cbuf[cidx0]);
            cold1 = ld_dev(&cbuf[cidx1]);
            float xv = x[(size_t)t * (B_ * N_) + (bA + half) * N_ + tt];
            __syncthreads();

            // fused: 64 we-iterations interleaved with 16 h-kc MFMA sets,
            // rolled (unroll 1), 1-ahead prefetch on the At/Wt streams.
            float accA = 0.f, accB = 0.f;
            const float4* wp4 = (const float4*)We_p;
            const size_t hb = (size_t)rtC * 16 * 64;
            size_t ai0 = (hb + lane) * 2;
            ull pah0 = ld_dev64(Hh + ai0), pah1 = ld_dev64(Hh + ai0 + 1);
            ull pal0 = ld_dev64(Hl + ai0), pal1 = ld_dev64(Hl + ai0 + 1);
            short8v pw0h = Wt_hi[(ctA * KC_ + 8) * 64 + lane];
            short8v pw0l = Wt_lo[(ctA * KC_ + 8) * 64 + lane];
            short8v pw1h = Wt_hi[(ctB * KC_ + 8) * 64 + lane];
            short8v pw1l = Wt_lo[(ctB * KC_ + 8) * 64 + lane];

#pragma unroll 1
            for (int i = 0; i < 16; i++) {
#pragma unroll
                for (int jq = 0; jq < 4; jq++) {
                    int q = qr * 64 + i * 4 + jq;
                    float4 wq = wp4[q * 128 + s_];
                    float4 a = *(const float4*)&hcA[q * 4];
                    float4 b2 = *(const float4*)&hcB[q * 4];
                    accA += wq.x * a.x + wq.y * a.y + wq.z * a.z + wq.w * a.w;
                    accB += wq.x * b2.x + wq.y * b2.y + wq.z * b2.z + wq.w * b2.w;
                }
                ull ah0 = pah0, ah1 = pah1, al0 = pal0, al1 = pal1;
                short8v w0h = pw0h, w0l = pw0l, w1h = pw1h, w1l = pw1l;
                if (i + 1 < 16) {
                    size_t an = (hb + (size_t)(i + 1) * 64 + lane) * 2;
                    pah0 = ld_dev64(Hh + an); pah1 = ld_dev64(Hh + an + 1);
                    pal0 = ld_dev64(Hl + an); pal1 = ld_dev64(Hl + an + 1);
                    pw0h = Wt_hi[(ctA * KC_ + 9 + i) * 64 + lane];
                    pw0l = Wt_lo[(ctA * KC_ + 9 + i) * 64 + lane];
                    pw1h = Wt_hi[(ctB * KC_ + 9 + i) * 64 + lane];
                    pw1l = Wt_lo[(ctB * KC_ + 9 + i) * 64 + lane];
                }
                union { ull u[2]; short8v s; } aH, aL;
                aH.u[0] = ah0; aH.u[1] = ah1;
                aL.u[0] = al0; aL.u[1] = al1;
                acc0 = __builtin_amdgcn_mfma_f32_16x16x32_bf16(aH.s, w0h, acc0, 0, 0, 0);
                acc1 = __builtin_amdgcn_mfma_f32_16x16x32_bf16(aH.s, w1h, acc1, 0, 0, 0);
                acc0 = __builtin_amdgcn_mfma_f32_16x16x32_bf16(aH.s, w0l, acc0, 0, 0, 0);
                acc1 = __builtin_amdgcn_mfma_f32_16x16x32_bf16(aH.s, w1l, acc1, 0, 0, 0);
                acc0 = __builtin_amdgcn_mfma_f32_16x16x32_bf16(aL.s, w0h, acc0, 0, 0, 0);
                acc1 = __builtin_amdgcn_mfma_f32_16x16x32_bf16(aL.s, w1h, acc1, 0, 0, 0);
            }
            wepartA[qr * 128 + s_] = accA;
            wepartB[qr * 128 + s_] = accB;
            __syncthreads();
            if (tid < 128) {
                float wb = We_b[tid];
                wv[0][tid * 2] = (wepartA[tid] + wepartA[128 + tid]
                                + wepartA[256 + tid] + wepartA[384 + tid] + wb) * 2.0f;
                wv[1][tid * 2] = (wepartB[tid] + wepartB[128 + tid]
                                + wepartB[256 + tid] + wepartB[384 + tid] + wb) * 2.0f;
            }
            __syncthreads();

            // attention: accumulate -2ve*rcp(exp(2z)+1) (Sum(ve) dropped)
            float e = 0.f;
#pragma unroll
            for (int i = 0; i < 64; i++) {
                unsigned u = ureg[i];
                float4 q = *(const float4*)&wv[half][i * 4];
                float z0 = q.x + __uint_as_float(u << 16);
                float z1 = q.z + __uint_as_float(u & 0xFFFF0000u);
                float r0 = __builtin_amdgcn_rcpf(__expf(z0) + 1.f);
                float r1 = __builtin_amdgcn_rcpf(__expf(z1) + 1.f);
                e = fmaf(-q.y, r0, e);
                e = fmaf(-q.w, r1, e);
            }

            // softmax over n (256 = 4 waves per half): shfl reduce + combine
            float m = e;
#pragma unroll
            for (int off = 32; off >= 1; off >>= 1)
                m = fmaxf(m, __shfl_xor(m, off));
            if (lane == 0) red[w] = m;
            __syncthreads();
            float mx = fmaxf(fmaxf(red[half * 4 + 0], red[half * 4 + 1]),
                             fmaxf(red[half * 4 + 2], red[half * 4 + 3]));
            float ex = __expf(e - mx);
            float sm = ex;
#pragma unroll
            for (int off = 32; off >= 1; off >>= 1)
                sm += __shfl_xor(sm, off);
            if (lane == 0) red[8 + w] = sm;
            __syncthreads();
            float denom = red[8 + half * 4 + 0] + red[8 + half * 4 + 1]
                        + red[8 + half * 4 + 2] + red[8 + half * 4 + 3];
            float alpha = __fdividef(ex, denom);
            xs[half][tt] = alpha * xv;
            __syncthreads();

            // ---- emit x~ region At (kc 0..7), single buffer ----
            if (tid >= 128 && tid < 192) {
                int u2 = tid - 128;
                int rowsel = u2 >> 5;
                int q2 = u2 & 31;
                int kc = q2 >> 2, qd = q2 & 3;
                int nb = kc * 32 + qd * 8;
                float v[8];
#pragma unroll
                for (int j = 0; j < 8; j++) v[j] = xs[rowsel][nb + j];
                int b2 = bA + rowsel;
                int rt = b2 >> 4;
                int ln = qd * 16 + (b2 & 15);
                size_t uidx = ((size_t)(rt * 8 + kc) * 64 + ln) * 2;
                unsigned short hi[8], lo[8];
#pragma unroll
                for (int j = 0; j < 8; j++) {
                    hi[j] = bf16_rne(v[j]);
                    lo[j] = bf16_rne(v[j] - bf16_tof(hi[j]));
                }
                st_dev64(Atx_hi + uidx,     pack4(hi));
                st_dev64(Atx_hi + uidx + 1, pack4(hi + 4));
                st_dev64(Atx_lo + uidx,     pack4(lo));
                st_dev64(Atx_lo + uidx + 1, pack4(lo + 4));
            }
        }
        group_bar(gbar, bgoal); bgoal += GSZ;

        // -------- Part C: x-part gates GEMM (8 kc) + cell + h-At emit -------
        {
            const size_t xb = (size_t)rtC * 8 * 64;
            size_t aidx = (xb + lane) * 2;
            ull pah0 = ld_dev64(Atx_hi + aidx), pah1 = ld_dev64(Atx_hi + aidx + 1);
            ull pal0 = ld_dev64(Atx_lo + aidx), pal1 = ld_dev64(Atx_lo + aidx + 1);
            short8v pw0h = Wt_hi[(ctA * KC_ + 0) * 64 + lane];
            short8v pw0l = Wt_lo[(ctA * KC_ + 0) * 64 + lane];
            short8v pw1h = Wt_hi[(ctB * KC_ + 0) * 64 + lane];
            short8v pw1l = Wt_lo[(ctB * KC_ + 0) * 64 + lane];

#pragma unroll 1
            for (int kc = 0; kc < 8; kc++) {
                ull ah0 = pah0, ah1 = pah1, al0 = pal0, al1 = pal1;
                short8v w0h = pw0h, w0l = pw0l, w1h = pw1h, w1l = pw1l;
                if (kc + 1 < 8) {
                    size_t ai = (xb + (size_t)(kc + 1) * 64 + lane) * 2;
                    pah0 = ld_dev64(Atx_hi + ai); pah1 = ld_dev64(Atx_hi + ai + 1);
                    pal0 = ld_dev64(Atx_lo + ai); pal1 = ld_dev64(Atx_lo + ai + 1);
                    pw0h = Wt_hi[(ctA * KC_ + kc + 1) * 64 + lane];
                    pw0l = Wt_lo[(ctA * KC_ + kc + 1) * 64 + lane];
                    pw1h = Wt_hi[(ctB * KC_ + kc + 1) * 64 + lane];
                    pw1l = Wt_lo[(ctB * KC_ + kc + 1) * 64 + lane];
                }
                union { ull u[2]; short8v s; } aH, aL;
                aH.u[0] = ah0; aH.u[1] = ah1;
                aL.u[0] = al0; aL.u[1] = al1;
                acc0 = __builtin_amdgcn_mfma_f32_16x16x32_bf16(aH.s, w0h, acc0, 0, 0, 0);
                acc1 = __builtin_amdgcn_mfma_f32_16x16x32_bf16(aH.s, w1h, acc1, 0, 0, 0);
                acc0 = __builtin_amdgcn_mfma_f32_16x16x32_bf16(aH.s, w0l, acc0, 0, 0, 0);
                acc1 = __builtin_amdgcn_mfma_f32_16x16x32_bf16(aH.s, w1l, acc1, 0, 0, 0);
                acc0 = __builtin_amdgcn_mfma_f32_16x16x32_bf16(aL.s, w0h, acc0, 0, 0, 0);
                acc1 = __builtin_amdgcn_mfma_f32_16x16x32_bf16(aL.s, w1h, acc1, 0, 0, 0);
            }

            // dump C/D (col=lane&15, row=quad*4+reg) into gates tile
            const int r0 = (w & 3) * 16;
            const int c0l = (w >> 2) * 32;
#pragma unroll
            for (int r = 0; r < 4; r++) {
                gates_s[r0 + quad * 4 + r][c0l + (lane & 15)] = acc0[r];
                gates_s[r0 + quad * 4 + r][c0l + 16 + (lane & 15)] = acc1[r];
            }
            __syncthreads();

            // fused cell: 2 cells/thread; stage h into LDS for the h-emit
            float* hseq_t = hseq + (size_t)t * (B_ * M_);
            {
                float gi = gates_s[b_l0][mi_c * 4 + 0] + bgi;
                float gf = gates_s[b_l0][mi_c * 4 + 1] + bgf;
                float gc = gates_s[b_l0][mi_c * 4 + 2] + bgc;
                float go = gates_s[b_l0][mi_c * 4 + 3] + bgo;
                float cn = fast_sig(gf) * cold0 + fast_sig(gi) * fast_tanh(gc);
                float hn = fast_sig(go) * fast_tanh(cn);
                st_dev(&cbuf[cidx0], cn);
                st_dev(&hseq_t[cidx0], hn);
                hn_s[b_l0][mi_c] = hn;
            }
            {
                float gi = gates_s[b_l0 + 32][mi_c * 4 + 0] + bgi;
                float gf = gates_s[b_l0 + 32][mi_c * 4 + 1] + bgf;
                float gc = gates_s[b_l0 + 32][mi_c * 4 + 2] + bgc;
                float go = gates_s[b_l0 + 32][mi_c * 4 + 3] + bgo;
                float cn = fast_sig(gf) * cold1 + fast_sig(gi) * fast_tanh(gc);
                float hn = fast_sig(go) * fast_tanh(cn);
                st_dev(&cbuf[cidx1], cn);
                st_dev(&hseq_t[cidx1], hn);
                hn_s[b_l0 + 32][mi_c] = hn;
            }
            __syncthreads();

            // h-At(t+1) emit (next parity) from hn_s: block sg owns cols
            // sg*16..+16 -> kh = sg>>1, qd = 2*(sg&1)+q  (round-3 mapping)
            if (t + 1 < T_ && tid < 128) {
                int rt_l = tid >> 5;
                int q = (tid >> 4) & 1;
                int b_lo = tid & 15;
                int b_local = rt_l * 16 + b_lo;
                float v[8];
#pragma unroll
                for (int j = 0; j < 8; j++) v[j] = hn_s[b_local][q * 8 + j];
                unsigned short hi[8], lo[8];
#pragma unroll
                for (int j = 0; j < 8; j++) {
                    hi[j] = bf16_rne(v[j]);
                    lo[j] = bf16_rne(v[j] - bf16_tof(hi[j]));
                }
                int kh = sg >> 1;
                int ln = (2 * (sg & 1) + q) * 16 + b_lo;
                size_t uidx = ((size_t)((g * 4 + rt_l) * 16 + kh) * 64 + ln) * 2;
                st_dev64(nHh + uidx,     pack4(hi));
                st_dev64(nHh + uidx + 1, pack4(hi + 4));
                st_dev64(nHl + uidx,     pack4(lo));
                st_dev64(nHl + uidx + 1, pack4(lo + 4));
            }
        }
        group_bar(gbar, bgoal); bgoal += GSZ;
    }
}

// ---------------------------------------------------------------------------
// Post: l[b,t] += sum_m tanh(h_seq@Ud_w^T + Ud_b)*vd_w   (rows=T*B, cols=M)
// ---------------------------------------------------------------------------
__global__ __launch_bounds__(256) void gemm_l(
    const float* __restrict__ A1,
    const float* __restrict__ W1,
    const float* __restrict__ bias1,
    const float* __restrict__ vw, float* __restrict__ lout)
{
    __shared__ float As[16][68];
    __shared__ float Ws[16][68];
    __shared__ float rsum[64];

    const int tid = threadIdx.x;
    const int tx = tid & 15, ty = tid >> 4;
    const int row0 = blockIdx.y * 64;
    const int col0 = blockIdx.x * 64;
    const int li = tid >> 2;
    const int lk4 = (tid & 3) * 4;

    float acc[4][4];
#pragma unroll
    for (int r = 0; r < 4; r++)
#pragma unroll
        for (int cc = 0; cc < 4; cc++) acc[r][cc] = 0.f;

    float4 av = *(const float4*)&A1[(size_t)(row0 + li) * M_ + lk4];
    float4 wvv = *(const float4*)&W1[(size_t)(col0 + li) * M_ + lk4];
#pragma unroll 1
    for (int kk = 0; kk < 512; kk += 16) {
        __syncthreads();
        As[lk4 + 0][li] = av.x; As[lk4 + 1][li] = av.y;
        As[lk4 + 2][li] = av.z; As[lk4 + 3][li] = av.w;
        Ws[lk4 + 0][li] = wvv.x; Ws[lk4 + 1][li] = wvv.y;
        Ws[lk4 + 2][li] = wvv.z; Ws[lk4 + 3][li] = wvv.w;
        __syncthreads();
        if (kk + 16 < 512) {
            av = *(const float4*)&A1[(size_t)(row0 + li) * M_ + kk + 16 + lk4];
            wvv = *(const float4*)&W1[(size_t)(col0 + li) * M_ + kk + 16 + lk4];
        }
#pragma unroll
        for (int k = 0; k < 16; k++) {
            float4 a = *(const float4*)&As[k][ty * 4];
            float4 w2 = *(const float4*)&Ws[k][tx * 4];
            acc[0][0] += a.x * w2.x; acc[0][1] += a.x * w2.y;
            acc[0][2] += a.x * w2.z; acc[0][3] += a.x * w2.w;
            acc[1][0] += a.y * w2.x; acc[1][1] += a.y * w2.y;
            acc[1][2] += a.y * w2.z; acc[1][3] += a.y * w2.w;
            acc[2][0] += a.z * w2.x; acc[2][1] += a.z * w2.y;
            acc[2][2] += a.z * w2.z; acc[2][3] += a.z * w2.w;
            acc[3][0] += a.w * w2.x; acc[3][1] += a.w * w2.y;
            acc[3][2] += a.w * w2.z; acc[3][3] += a.w * w2.w;
        }
    }

    __syncthreads();
    if (tid < 64) rsum[tid] = 0.f;
    __syncthreads();
    float part[4] = {0.f, 0.f, 0.f, 0.f};
#pragma unroll
    for (int r = 0; r < 4; r++)
#pragma unroll
        for (int cc = 0; cc < 4; cc++) {
            int gc = col0 + tx * 4 + cc;
            part[r] += fast_tanh(acc[r][cc] + bias1[gc]) * vw[gc];
        }
#pragma unroll
    for (int r = 0; r < 4; r++)
        atomicAdd(&rsum[ty * 4 + r], part[r]);
    __syncthreads();
    if (tid < 64) {
        int gr = row0 + tid;          // gr = t*512 + b
        int b = gr & 511, t = gr >> 9;
        atomicAdd(&lout[b * 128 + t], rsum[tid]);
    }
}

// ---------------------------------------------------------------------------
// Final: beta = softmax_t(l); ctx = sum_t beta*h_seq; logits = ctx.out_w+out_b
// ---------------------------------------------------------------------------
__global__ __launch_bounds__(512) void final_kernel(
    const float* __restrict__ lbuf, const float* __restrict__ hseq,
    const float* __restrict__ out_w, const float* __restrict__ out_b,
    float* __restrict__ out)
{
    const int b = blockIdx.x;
    const int tid = threadIdx.x;
    __shared__ float beta_s[128];
    __shared__ float red[512];

    float lv = (tid < 128) ? lbuf[b * 128 + tid] : -1e30f;
    red[tid] = lv; __syncthreads();
    for (int off = 256; off >= 1; off >>= 1) {
        if (tid < off) red[tid] = fmaxf(red[tid], red[tid + off]);
        __syncthreads();
    }
    float mx = red[0]; __syncthreads();
    float ex = (tid < 128) ? __expf(lv - mx) : 0.f;
    red[tid] = ex; __syncthreads();
    for (int off = 256; off >= 1; off >>= 1) {
        if (tid < off) red[tid] += red[tid + off];
        __syncthreads();
    }
    float denom = red[0];
    if (tid < 128) {
        float bt = ex / denom;
        beta_s[tid] = bt;
        out[512 + b * 128 + tid] = bt;
    }
    __syncthreads();

    float ctx = 0.f;
#pragma unroll 4
    for (int t = 0; t < 128; t++)
        ctx += beta_s[t] * hseq[(size_t)t * (B_ * M_) + b * M_ + tid];

    red[tid] = ctx * out_w[tid]; __syncthreads();
    for (int off = 256; off >= 1; off >>= 1) {
        if (tid < off) red[tid] += red[tid + off];
        __syncthreads();
    }
    if (tid == 0) out[b] = red[0] + out_b[0];
}

// ---------------------------------------------------------------------------
extern "C" void kernel_launch(void* const* d_in, const int* in_sizes, int n_in,
                              void* d_out, int out_size, void* d_ws, size_t ws_size,
                              hipStream_t stream)
{
    const float* x    = (const float*)d_in[0];
    const float* h0   = (const float*)d_in[1];
    const float* c0   = (const float*)d_in[2];
    const float* Wih  = (const float*)d_in[3];
    const float* Whh  = (const float*)d_in[4];
    const float* b_ih = (const float*)d_in[5];
    const float* b_hh = (const float*)d_in[6];
    const float* We_w = (const float*)d_in[7];
    const float* We_b = (const float*)d_in[8];
    const float* Ue_w = (const float*)d_in[9];
    const float* Ue_b = (const float*)d_in[10];
    const float* ve_w = (const float*)d_in[11];
    const float* Ud_w = (const float*)d_in[13];
    const float* Ud_b = (const float*)d_in[14];
    const float* vd_w = (const float*)d_in[15];
    const float* out_w = (const float*)d_in[17];
    const float* out_b = (const float*)d_in[18];
    float* out = (float*)d_out;

    // workspace layout (float slots). lbuf aliases ue_pk (disjoint lifetimes).
    float* ws     = (float*)d_ws;
    float* ue_pk  = ws;                       //  8,388,608 (B*64*N uints) [scan]
    float* lbuf   = ws;                       //     65,536 (B*T)   [post only]
    float* hseq   = ws + 8388608;             // 33,554,432 (T*B*M)
    float* cbuf   = hseq + 33554432;          //    262,144 (B*M)
    float* We_p   = cbuf + 262144;            //    131,072
    float* bgv    = We_p + 131072;            //      2,048
    float* Atx_hi = bgv + 2048;               //     65,536 (32rt*8kc*64*16B)
    float* Atx_lo = Atx_hi + 65536;           //     65,536
    float* Ath_hi0= Atx_lo + 65536;           //    131,072 (32rt*16kc*64*16B)
    float* Ath_lo0= Ath_hi0 + 131072;         //    131,072
    float* Ath_hi1= Ath_lo0 + 131072;         //    131,072
    float* Ath_lo1= Ath_hi1 + 131072;         //    131,072
    float* Wt_hi  = Ath_lo1 + 131072;         //    786,432
    float* Wt_lo  = Wt_hi + 786432;           //    786,432
    int*   bar    = (int*)(Wt_lo + 786432);   //  8*32 ints

    hipMemcpyAsync(cbuf, c0, (size_t)B_ * M_ * 4, hipMemcpyDeviceToDevice, stream);
    hipMemsetAsync(bar, 0, 8 * 32 * 4, stream);

    prep_bg<<<8, 256, 0, stream>>>(b_ih, b_hh, bgv);
    prep_wt<<<768, 256, 0, stream>>>(Wih, Whh, (uint4*)Wt_hi, (uint4*)Wt_lo);
    prep_wep<<<512, 256, 0, stream>>>(We_w, We_p);
    ue_pre<<<dim3(4, 512), 256, 0, stream>>>(x, Ue_w, Ue_b, (unsigned*)ue_pk);

    scan_persist<<<NBLK, 512, 0, stream>>>(
        x, h0, We_p, We_b, ve_w, (const unsigned*)ue_pk,
        (const short8v*)Wt_hi, (const short8v*)Wt_lo, bgv,
        cbuf, hseq,
        (ull*)Atx_hi, (ull*)Atx_lo,
        (ull*)Ath_hi0, (ull*)Ath_lo0, (ull*)Ath_hi1, (ull*)Ath_lo1,
        bar);

    hipMemsetAsync(lbuf, 0, (size_t)B_ * T_ * 4, stream);
    gemm_l<<<dim3(8, 1024), 256, 0, stream>>>(hseq, Ud_w, Ud_b, vd_w, lbuf);
    final_kernel<<<512, 512, 0, stream>>>(lbuf, hseq, out_w, out_b, out);
}

// Round 8
// 3996.246 us; speedup vs baseline: 1.5831x; 1.5831x over previous
//
#include <hip/hip_runtime.h>
#include <math.h>

// Problem dims
#define T_ 128
#define B_ 512
#define N_ 256
#define M_ 512
#define G_ 2048   // 4*M
#define NBLK 256  // 8 groups x 32 blocks, 1 block/CU, 512 threads = 8 waves/CU
#define GSZ 32    // blocks per group
#define KC_ 24    // K chunks of 32 (768 total: 256 x-tilde + 512 h)

typedef unsigned long long ull;
typedef __attribute__((ext_vector_type(8))) _Float16 half8v;
typedef __attribute__((ext_vector_type(4))) float float4v;

// ---------------------------------------------------------------------------
// Device-coherent access, relaxed: cross-XCD safe
// ---------------------------------------------------------------------------
__device__ __forceinline__ float ld_dev(const float* p) {
    return __hip_atomic_load(const_cast<float*>(p), __ATOMIC_RELAXED,
                             __HIP_MEMORY_SCOPE_AGENT);
}
__device__ __forceinline__ void st_dev(float* p, float v) {
    __hip_atomic_store(p, v, __ATOMIC_RELAXED, __HIP_MEMORY_SCOPE_AGENT);
}
__device__ __forceinline__ ull ld_dev64(const ull* p) {
    return __hip_atomic_load(const_cast<ull*>(p), __ATOMIC_RELAXED,
                             __HIP_MEMORY_SCOPE_AGENT);
}
__device__ __forceinline__ void st_dev64(ull* p, ull v) {
    __hip_atomic_store(p, v, __ATOMIC_RELAXED, __HIP_MEMORY_SCOPE_AGENT);
}

// Fast transcendentals (abs err ~1e-6, threshold 1e-3)
__device__ __forceinline__ float fast_tanh(float x) {
    float e = __expf(2.f * x);
    return 1.f - __fdividef(2.f, e + 1.f);
}
__device__ __forceinline__ float fast_sig(float x) {
    return __fdividef(1.f, 1.f + __expf(-x));
}

// bf16 helpers (RNE) — still used for the ue path
__device__ __forceinline__ unsigned short bf16_rne(float f) {
    unsigned u = __float_as_uint(f);
    return (unsigned short)((u + 0x7FFFu + ((u >> 16) & 1u)) >> 16);
}
// fp16 bits (RNE via hardware cvt)
__device__ __forceinline__ unsigned short f16_bits(float f) {
    union { _Float16 h; unsigned short u; } cv;
    cv.h = (_Float16)f;
    return cv.u;
}
__device__ __forceinline__ ull pack4(const unsigned short* s) {
    return (ull)s[0] | ((ull)s[1] << 16) | ((ull)s[2] << 32) | ((ull)s[3] << 48);
}

// ---------------------------------------------------------------------------
// Group barrier: 32 blocks, relaxed ticket, no L2 flush.
// ---------------------------------------------------------------------------
__device__ __forceinline__ void group_bar(int* gbar, int goal) {
    __syncthreads();
    if (threadIdx.x == 0) {
        asm volatile("s_waitcnt vmcnt(0)" ::: "memory");
        __hip_atomic_fetch_add(gbar, 1, __ATOMIC_RELAXED,
                               __HIP_MEMORY_SCOPE_AGENT);
        while (__hip_atomic_load(gbar, __ATOMIC_RELAXED,
                                 __HIP_MEMORY_SCOPE_AGENT) < goal) {
            __builtin_amdgcn_s_sleep(1);
        }
    }
    __syncthreads();
}

// ---------------------------------------------------------------------------
// Prep: fused bias bg[4m+g] = b_ih[g*512+m] + b_hh[g*512+m]
// ---------------------------------------------------------------------------
__global__ __launch_bounds__(256) void prep_bg(
    const float* __restrict__ bih, const float* __restrict__ bhh,
    float* __restrict__ bg)
{
    int rp = blockIdx.x * 256 + threadIdx.x;
    if (rp < 2048) {
        int m = rp >> 2, g = rp & 3;
        int row = g * 512 + m;
        bg[rp] = bih[row] + bhh[row];
    }
}

// ---------------------------------------------------------------------------
// Prep: Wt fragment-tiled SINGLE-PLANE fp16 (halves the L2-resident slice
// per XCD 768->384 KB and the per-kc load volume vs the bf16 hi/lo scheme).
// ---------------------------------------------------------------------------
__global__ __launch_bounds__(256) void prep_wt(
    const float* __restrict__ Wih, const float* __restrict__ Whh,
    uint4* __restrict__ Wt)
{
    int uid = blockIdx.x * 256 + threadIdx.x;   // < 196608
    int ct = uid / (KC_ * 64);
    int rem = uid % (KC_ * 64);
    int kc = rem >> 6, lane = rem & 63;
    int col = ct * 16 + (lane & 15);
    int m = col >> 2, gi = col & 3;
    int grow = gi * 512 + m;
    int quad = lane >> 4;
    union { unsigned short s[8]; uint4 v; } o;
#pragma unroll
    for (int j = 0; j < 8; j++) {
        int k = kc * 32 + quad * 8 + j;
        float v = (k < 256) ? Wih[(size_t)grow * 256 + k]
                            : Whh[(size_t)grow * 512 + (k - 256)];
        o.s[j] = f16_bits(v);
    }
    Wt[uid] = o.v;
}

// We_p[q][s][j] = We_w[s][q*4+j]   (f32 — bf16 variant regressed, round 6)
__global__ __launch_bounds__(256) void prep_wep(
    const float* __restrict__ We_w, float* __restrict__ We_p)
{
    int idx = blockIdx.x * 256 + threadIdx.x;   // < 131072
    int q = idx >> 9, rest = idx & 511, s = rest >> 2, j = rest & 3;
    We_p[idx] = We_w[s * 1024 + q * 4 + j];
}

// ---------------------------------------------------------------------------
// Precompute (Ue_x + Ue_b) * 2, packed bf16 s-pairs.
// ---------------------------------------------------------------------------
__global__ __launch_bounds__(256) void ue_pre(
    const float* __restrict__ x, const float* __restrict__ Ue_w,
    const float* __restrict__ Ue_b, unsigned* __restrict__ ue_pk)
{
    const int b = blockIdx.y;
    const int s0 = blockIdx.x * 32;
    const int n = threadIdx.x;
    __shared__ float xs[32][256];
    __shared__ float uws[32][32];

    float acc[32];
#pragma unroll
    for (int i = 0; i < 32; i++) acc[i] = 0.f;

#pragma unroll 1
    for (int tc = 0; tc < 4; tc++) {
        __syncthreads();
#pragma unroll
        for (int tt = 0; tt < 32; tt++)
            xs[tt][n] = x[(size_t)(tc * 32 + tt) * (B_ * N_) + b * N_ + n];
#pragma unroll
        for (int q = 0; q < 4; q++) {
            int e = q * 256 + n;
            int s = e >> 5, tt = e & 31;
            uws[s][tt] = Ue_w[(s0 + s) * T_ + tc * 32 + tt];
        }
        __syncthreads();
        float xr[32];
#pragma unroll
        for (int tt = 0; tt < 32; tt++) xr[tt] = xs[tt][n];
#pragma unroll
        for (int s = 0; s < 32; s++) {
            float a = acc[s];
#pragma unroll
            for (int tt = 0; tt < 32; tt++) a += xr[tt] * uws[s][tt];
            acc[s] = a;
        }
    }
#pragma unroll
    for (int i = 0; i < 16; i++) {
        float v0 = (acc[2 * i] + Ue_b[s0 + 2 * i]) * 2.0f;
        float v1 = (acc[2 * i + 1] + Ue_b[s0 + 2 * i + 1]) * 2.0f;
        unsigned pk = (unsigned)bf16_rne(v0) | ((unsigned)bf16_rne(v1) << 16);
        ue_pk[((size_t)b * 64 + (s0 >> 1) + i) * 256 + n] = pk;
    }
}

// ---------------------------------------------------------------------------
// Persistent scan = round-2 structure FROZEN (barriers, thread mappings,
// 1-ahead rolled Part C — 5 restructure attempts all thrashed per-XCD L2).
// This round's single change: the gates GEMM runs single-plane FP16
// (mfma_f32_16x16x32_f16) instead of bf16 hi/lo: At 1.5->0.75 MB,
// Wt 6->3 MB, 6->2 MFMAs/kc, half the At load volume per kc.
// Accuracy: fp16 gate error ~1.4e-4, damped LSTM recurrence -> absmax
// predicted 1-4e-4 < 1e-3 threshold. Attention/we path unchanged (f32).
// ---------------------------------------------------------------------------
__global__ __launch_bounds__(512, 1) void scan_persist(
    const float* __restrict__ x, const float* __restrict__ h0,
    const float* __restrict__ We_p, const float* __restrict__ We_b,
    const float* __restrict__ ve_w, const unsigned* __restrict__ ue_pk,
    const half8v* __restrict__ Wt,
    const float* __restrict__ bg,
    float* __restrict__ cbuf, float* __restrict__ hseq,
    ull* __restrict__ At, int* bar)
{
    const int tid = threadIdx.x;
    const int blk = blockIdx.x;
    const int g = blk >> 5;          // group 0..7
    const int sg = blk & 31;         // slot in group
    int* gbar = bar + g * 32;

    __shared__ __align__(16) float hcA[1024];
    __shared__ __align__(16) float hcB[1024];
    __shared__ float wepartA[512];
    __shared__ float wepartB[512];
    __shared__ __align__(16) float wv[2][256];   // [half][s*2+{2*we, 2*ve}]
    __shared__ float red[16];
    __shared__ float xs[2][256];
    __shared__ float gates_s[64][65];

    // part A ids
    const int bA = g * 64 + sg * 2;
    const int bB = bA + 1;
    const int s_ = tid & 127;
    const int qr = tid >> 7;
    const int half = tid >> 8;       // batch half (wave-uniform)
    const int tt = tid & 255;        // n
    // part C ids
    const int lane = tid & 63;
    const int w = tid >> 6;          // wave 0..7
    const int rtC = g * 4 + (w & 3);
    const int ctA = sg * 4 + (w >> 2) * 2;
    const int ctB = ctA + 1;
    const int quad = lane >> 4;
    // cell ids (loop-invariant)
    const int mi_c = tid & 15;
    const int b_l0 = tid >> 4;                   // 0..31
    const int cidx0 = (g * 64 + b_l0) * M_ + sg * 16 + mi_c;
    const int cidx1 = cidx0 + 32 * M_;

    if (tid < 128) {
        float v = 2.0f * ve_w[tid];  // pre-doubled: e -= (2*ve) * rcp(E+1)
        wv[0][tid * 2 + 1] = v;
        wv[1][tid * 2 + 1] = v;
    }

    // loop-invariant fused biases for this thread's cells
    const float bgi = bg[sg * 64 + mi_c * 4 + 0];
    const float bgf = bg[sg * 64 + mi_c * 4 + 1];
    const float bgc = bg[sg * 64 + mi_c * 4 + 2];
    const float bgo = bg[sg * 64 + mi_c * 4 + 3];

    // ---- one-time: load this thread's ue slice (all 128 s) into VGPRs ----
    unsigned ureg[64];
    {
        const unsigned* up = ue_pk + ((size_t)(bA + half) * 64) * 256 + tt;
#pragma unroll
        for (int i = 0; i < 64; i++) ureg[i] = up[(size_t)i * 256];
    }

#pragma unroll 1
    for (int t = 0; t < T_; t++) {
        const float* hprev = t ? (hseq + (size_t)(t - 1) * (B_ * M_)) : h0;

        // ---------------- Part A ----------------
        {
            hcA[tid]       = ld_dev(hprev + bA * M_ + tid);
            hcA[512 + tid] = ld_dev(cbuf + bA * M_ + tid);
            hcB[tid]       = ld_dev(hprev + bB * M_ + tid);
            hcB[512 + tid] = ld_dev(cbuf + bB * M_ + tid);
            // hoist x read above the attention loop (independent)
            float xv = x[(size_t)t * (B_ * N_) + (bA + half) * N_ + tt];
            __syncthreads();

            // ---- emit h-region At (kc 8..23) EARLY: only needs h(t-1);
            //      stores drain under we-GEMM + attention compute ----
            if (tid < 128) {
                int rowsel = tid >> 6;
                int q2 = tid & 63;
                int kc = 8 + (q2 >> 2), qd = q2 & 3;
                const float* hcX = rowsel ? hcB : hcA;
                int mb = (kc - 8) * 32 + qd * 8;
                float v[8];
#pragma unroll
                for (int j = 0; j < 8; j++) v[j] = hcX[mb + j];
                int b2 = bA + rowsel;
                int rt = b2 >> 4;
                int ln = qd * 16 + (b2 & 15);
                size_t uidx = ((size_t)(rt * KC_ + kc) * 64 + ln) * 2;
                unsigned short fh[8];
#pragma unroll
                for (int j = 0; j < 8; j++) fh[j] = f16_bits(v[j]);
                st_dev64(At + uidx,     pack4(fh));
                st_dev64(At + uidx + 1, pack4(fh + 4));
            }

            // we partials: 4-way K split, shared f32 We_p stream
            float accA = 0.f, accB = 0.f;
            const float4* wp4 = (const float4*)We_p;
#pragma unroll 4
            for (int q = qr * 64; q < qr * 64 + 64; q++) {
                float4 wq = wp4[q * 128 + s_];
                float4 a = *(const float4*)&hcA[q * 4];
                float4 b2 = *(const float4*)&hcB[q * 4];
                accA += wq.x * a.x + wq.y * a.y + wq.z * a.z + wq.w * a.w;
                accB += wq.x * b2.x + wq.y * b2.y + wq.z * b2.z + wq.w * b2.w;
            }
            wepartA[qr * 128 + s_] = accA;
            wepartB[qr * 128 + s_] = accB;
            __syncthreads();
            if (tid < 128) {
                float wb = We_b[tid];
                wv[0][tid * 2] = (wepartA[tid] + wepartA[128 + tid]
                                + wepartA[256 + tid] + wepartA[384 + tid] + wb) * 2.0f;
                wv[1][tid * 2] = (wepartB[tid] + wepartB[128 + tid]
                                + wepartB[256 + tid] + wepartB[384 + tid] + wb) * 2.0f;
            }
            __syncthreads();

            // attention: accumulate -2ve*rcp(exp(2z)+1) (Sum(ve) dropped)
            float e = 0.f;
#pragma unroll
            for (int i = 0; i < 64; i++) {
                unsigned u = ureg[i];
                float4 q = *(const float4*)&wv[half][i * 4];
                float z0 = q.x + __uint_as_float(u << 16);
                float z1 = q.z + __uint_as_float(u & 0xFFFF0000u);
                float r0 = __builtin_amdgcn_rcpf(__expf(z0) + 1.f);
                float r1 = __builtin_amdgcn_rcpf(__expf(z1) + 1.f);
                e = fmaf(-q.y, r0, e);
                e = fmaf(-q.w, r1, e);
            }

            // softmax over n (256 = 4 waves per half): shfl reduce + combine
            float m = e;
#pragma unroll
            for (int off = 32; off >= 1; off >>= 1)
                m = fmaxf(m, __shfl_xor(m, off));
            if (lane == 0) red[w] = m;
            __syncthreads();
            float mx = fmaxf(fmaxf(red[half * 4 + 0], red[half * 4 + 1]),
                             fmaxf(red[half * 4 + 2], red[half * 4 + 3]));
            float ex = __expf(e - mx);
            float sm = ex;
#pragma unroll
            for (int off = 32; off >= 1; off >>= 1)
                sm += __shfl_xor(sm, off);
            if (lane == 0) red[8 + w] = sm;
            __syncthreads();
            float denom = red[8 + half * 4 + 0] + red[8 + half * 4 + 1]
                        + red[8 + half * 4 + 2] + red[8 + half * 4 + 3];
            float alpha = __fdividef(ex, denom);
            xs[half][tt] = alpha * xv;
            __syncthreads();

            // ---- emit x~ region At (kc 0..7) ----
            if (tid >= 128 && tid < 192) {
                int u2 = tid - 128;
                int rowsel = u2 >> 5;
                int q2 = u2 & 31;
                int kc = q2 >> 2, qd = q2 & 3;
                int nb = kc * 32 + qd * 8;
                float v[8];
#pragma unroll
                for (int j = 0; j < 8; j++) v[j] = xs[rowsel][nb + j];
                int b2 = bA + rowsel;
                int rt = b2 >> 4;
                int ln = qd * 16 + (b2 & 15);
                size_t uidx = ((size_t)(rt * KC_ + kc) * 64 + ln) * 2;
                unsigned short fh[8];
#pragma unroll
                for (int j = 0; j < 8; j++) fh[j] = f16_bits(v[j]);
                st_dev64(At + uidx,     pack4(fh));
                st_dev64(At + uidx + 1, pack4(fh + 4));
            }
        }
        group_bar(gbar, (t * 2 + 1) * GSZ);

        // -------- Part C: fp16 gates GEMM (R2 1-ahead structure) + cell -----
        {
            // prefetch this thread's cell state early (same-thread RAW,
            // relaxed is sufficient); hides latency under the GEMM
            float cold0 = ld_dev(&cbuf[cidx0]);
            float cold1 = ld_dev(&cbuf[cidx1]);

            float4v acc0 = {0.f, 0.f, 0.f, 0.f};
            float4v acc1 = {0.f, 0.f, 0.f, 0.f};

            size_t aidx = ((size_t)(rtC * KC_ + 0) * 64 + lane) * 2;
            ull pa0 = ld_dev64(At + aidx), pa1 = ld_dev64(At + aidx + 1);
            half8v pw0 = Wt[(ctA * KC_ + 0) * 64 + lane];
            half8v pw1 = Wt[(ctB * KC_ + 0) * 64 + lane];

#pragma unroll 1
            for (int kc = 0; kc < KC_; kc++) {
                ull a0 = pa0, a1 = pa1;
                half8v w0 = pw0, w1 = pw1;
                if (kc + 1 < KC_) {
                    size_t ai = ((size_t)(rtC * KC_ + kc + 1) * 64 + lane) * 2;
                    pa0 = ld_dev64(At + ai); pa1 = ld_dev64(At + ai + 1);
                    pw0 = Wt[(ctA * KC_ + kc + 1) * 64 + lane];
                    pw1 = Wt[(ctB * KC_ + kc + 1) * 64 + lane];
                }
                union { ull u[2]; half8v h; } av;
                av.u[0] = a0; av.u[1] = a1;
                acc0 = __builtin_amdgcn_mfma_f32_16x16x32_f16(av.h, w0, acc0, 0, 0, 0);
                acc1 = __builtin_amdgcn_mfma_f32_16x16x32_f16(av.h, w1, acc1, 0, 0, 0);
            }

            // dump C/D (col=lane&15, row=quad*4+reg) into gates tile
            const int r0 = (w & 3) * 16;
            const int c0l = (w >> 2) * 32;
#pragma unroll
            for (int r = 0; r < 4; r++) {
                gates_s[r0 + quad * 4 + r][c0l + (lane & 15)] = acc0[r];
                gates_s[r0 + quad * 4 + r][c0l + 16 + (lane & 15)] = acc1[r];
            }
            __syncthreads();

            // fused cell: this thread's 2 cells (b_l0, mi_c), (b_l0+32, mi_c)
            float* hseq_t = hseq + (size_t)t * (B_ * M_);
            {
                float gi = gates_s[b_l0][mi_c * 4 + 0] + bgi;
                float gf = gates_s[b_l0][mi_c * 4 + 1] + bgf;
                float gc = gates_s[b_l0][mi_c * 4 + 2] + bgc;
                float go = gates_s[b_l0][mi_c * 4 + 3] + bgo;
                float cn = fast_sig(gf) * cold0 + fast_sig(gi) * fast_tanh(gc);
                st_dev(&cbuf[cidx0], cn);
                st_dev(&hseq_t[cidx0], fast_sig(go) * fast_tanh(cn));
            }
            {
                float gi = gates_s[b_l0 + 32][mi_c * 4 + 0] + bgi;
                float gf = gates_s[b_l0 + 32][mi_c * 4 + 1] + bgf;
                float gc = gates_s[b_l0 + 32][mi_c * 4 + 2] + bgc;
                float go = gates_s[b_l0 + 32][mi_c * 4 + 3] + bgo;
                float cn = fast_sig(gf) * cold1 + fast_sig(gi) * fast_tanh(gc);
                st_dev(&cbuf[cidx1], cn);
                st_dev(&hseq_t[cidx1], fast_sig(go) * fast_tanh(cn));
            }
        }
        group_bar(gbar, (t * 2 + 2) * GSZ);
    }
}

// ---------------------------------------------------------------------------
// Post: l[b,t] += sum_m tanh(h_seq@Ud_w^T + Ud_b)*vd_w   (rows=T*B, cols=M)
// ---------------------------------------------------------------------------
__global__ __launch_bounds__(256) void gemm_l(
    const float* __restrict__ A1,
    const float* __restrict__ W1,
    const float* __restrict__ bias1,
    const float* __restrict__ vw, float* __restrict__ lout)
{
    __shared__ float As[16][68];
    __shared__ float Ws[16][68];
    __shared__ float rsum[64];

    const int tid = threadIdx.x;
    const int tx = tid & 15, ty = tid >> 4;
    const int row0 = blockIdx.y * 64;
    const int col0 = blockIdx.x * 64;
    const int li = tid >> 2;
    const int lk4 = (tid & 3) * 4;

    float acc[4][4];
#pragma unroll
    for (int r = 0; r < 4; r++)
#pragma unroll
        for (int cc = 0; cc < 4; cc++) acc[r][cc] = 0.f;

    float4 av = *(const float4*)&A1[(size_t)(row0 + li) * M_ + lk4];
    float4 wvv = *(const float4*)&W1[(size_t)(col0 + li) * M_ + lk4];
#pragma unroll 1
    for (int kk = 0; kk < 512; kk += 16) {
        __syncthreads();
        As[lk4 + 0][li] = av.x; As[lk4 + 1][li] = av.y;
        As[lk4 + 2][li] = av.z; As[lk4 + 3][li] = av.w;
        Ws[lk4 + 0][li] = wvv.x; Ws[lk4 + 1][li] = wvv.y;
        Ws[lk4 + 2][li] = wvv.z; Ws[lk4 + 3][li] = wvv.w;
        __syncthreads();
        if (kk + 16 < 512) {
            av = *(const float4*)&A1[(size_t)(row0 + li) * M_ + kk + 16 + lk4];
            wvv = *(const float4*)&W1[(size_t)(col0 + li) * M_ + kk + 16 + lk4];
        }
#pragma unroll
        for (int k = 0; k < 16; k++) {
            float4 a = *(const float4*)&As[k][ty * 4];
            float4 w2 = *(const float4*)&Ws[k][tx * 4];
            acc[0][0] += a.x * w2.x; acc[0][1] += a.x * w2.y;
            acc[0][2] += a.x * w2.z; acc[0][3] += a.x * w2.w;
            acc[1][0] += a.y * w2.x; acc[1][1] += a.y * w2.y;
            acc[1][2] += a.y * w2.z; acc[1][3] += a.y * w2.w;
            acc[2][0] += a.z * w2.x; acc[2][1] += a.z * w2.y;
            acc[2][2] += a.z * w2.z; acc[2][3] += a.z * w2.w;
            acc[3][0] += a.w * w2.x; acc[3][1] += a.w * w2.y;
            acc[3][2] += a.w * w2.z; acc[3][3] += a.w * w2.w;
        }
    }

    __syncthreads();
    if (tid < 64) rsum[tid] = 0.f;
    __syncthreads();
    float part[4] = {0.f, 0.f, 0.f, 0.f};
#pragma unroll
    for (int r = 0; r < 4; r++)
#pragma unroll
        for (int cc = 0; cc < 4; cc++) {
            int gc = col0 + tx * 4 + cc;
            part[r] += fast_tanh(acc[r][cc] + bias1[gc]) * vw[gc];
        }
#pragma unroll
    for (int r = 0; r < 4; r++)
        atomicAdd(&rsum[ty * 4 + r], part[r]);
    __syncthreads();
    if (tid < 64) {
        int gr = row0 + tid;          // gr = t*512 + b
        int b = gr & 511, t = gr >> 9;
        atomicAdd(&lout[b * 128 + t], rsum[tid]);
    }
}

// ---------------------------------------------------------------------------
// Final: beta = softmax_t(l); ctx = sum_t beta*h_seq; logits = ctx.out_w+out_b
// ---------------------------------------------------------------------------
__global__ __launch_bounds__(512) void final_kernel(
    const float* __restrict__ lbuf, const float* __restrict__ hseq,
    const float* __restrict__ out_w, const float* __restrict__ out_b,
    float* __restrict__ out)
{
    const int b = blockIdx.x;
    const int tid = threadIdx.x;
    __shared__ float beta_s[128];
    __shared__ float red[512];

    float lv = (tid < 128) ? lbuf[b * 128 + tid] : -1e30f;
    red[tid] = lv; __syncthreads();
    for (int off = 256; off >= 1; off >>= 1) {
        if (tid < off) red[tid] = fmaxf(red[tid], red[tid + off]);
        __syncthreads();
    }
    float mx = red[0]; __syncthreads();
    float ex = (tid < 128) ? __expf(lv - mx) : 0.f;
    red[tid] = ex; __syncthreads();
    for (int off = 256; off >= 1; off >>= 1) {
        if (tid < off) red[tid] += red[tid + off];
        __syncthreads();
    }
    float denom = red[0];
    if (tid < 128) {
        float bt = ex / denom;
        beta_s[tid] = bt;
        out[512 + b * 128 + tid] = bt;
    }
    __syncthreads();

    float ctx = 0.f;
#pragma unroll 4
    for (int t = 0; t < 128; t++)
        ctx += beta_s[t] * hseq[(size_t)t * (B_ * M_) + b * M_ + tid];

    red[tid] = ctx * out_w[tid]; __syncthreads();
    for (int off = 256; off >= 1; off >>= 1) {
        if (tid < off) red[tid] += red[tid + off];
        __syncthreads();
    }
    if (tid == 0) out[b] = red[0] + out_b[0];
}

// ---------------------------------------------------------------------------
extern "C" void kernel_launch(void* const* d_in, const int* in_sizes, int n_in,
                              void* d_out, int out_size, void* d_ws, size_t ws_size,
                              hipStream_t stream)
{
    const float* x    = (const float*)d_in[0];
    const float* h0   = (const float*)d_in[1];
    const float* c0   = (const float*)d_in[2];
    const float* Wih  = (const float*)d_in[3];
    const float* Whh  = (const float*)d_in[4];
    const float* b_ih = (const float*)d_in[5];
    const float* b_hh = (const float*)d_in[6];
    const float* We_w = (const float*)d_in[7];
    const float* We_b = (const float*)d_in[8];
    const float* Ue_w = (const float*)d_in[9];
    const float* Ue_b = (const float*)d_in[10];
    const float* ve_w = (const float*)d_in[11];
    const float* Ud_w = (const float*)d_in[13];
    const float* Ud_b = (const float*)d_in[14];
    const float* vd_w = (const float*)d_in[15];
    const float* out_w = (const float*)d_in[17];
    const float* out_b = (const float*)d_in[18];
    float* out = (float*)d_out;

    // workspace layout (float slots). lbuf aliases ue_pk (disjoint lifetimes).
    float* ws    = (float*)d_ws;
    float* ue_pk = ws;                       //  8,388,608  (B*64*N uints) [scan]
    float* lbuf  = ws;                       //     65,536  (B*T)   [post only]
    float* hseq  = ue_pk + 8388608;          // 33,554,432  (T*B*M)
    float* cbuf  = hseq + 33554432;          //    262,144  (B*M)
    float* We_p  = cbuf + 262144;            //    131,072
    float* bgv   = We_p + 131072;            //      2,048
    float* At_f  = bgv + 2048;               //    196,608  (32*24*64*8 fp16)
    float* Wt_f  = At_f + 196608;            //    786,432  (128*24*64*8 fp16)
    int*   bar   = (int*)(Wt_f + 786432);    //   8*32 ints

    hipMemcpyAsync(cbuf, c0, (size_t)B_ * M_ * 4, hipMemcpyDeviceToDevice, stream);
    hipMemsetAsync(bar, 0, 8 * 32 * 4, stream);

    prep_bg<<<8, 256, 0, stream>>>(b_ih, b_hh, bgv);
    prep_wt<<<768, 256, 0, stream>>>(Wih, Whh, (uint4*)Wt_f);
    prep_wep<<<512, 256, 0, stream>>>(We_w, We_p);
    ue_pre<<<dim3(4, 512), 256, 0, stream>>>(x, Ue_w, Ue_b, (unsigned*)ue_pk);

    scan_persist<<<NBLK, 512, 0, stream>>>(
        x, h0, We_p, We_b, ve_w, (const unsigned*)ue_pk,
        (const half8v*)Wt_f, bgv,
        cbuf, hseq, (ull*)At_f, bar);

    hipMemsetAsync(lbuf, 0, (size_t)B_ * T_ * 4, stream);
    gemm_l<<<dim3(8, 1024), 256, 0, stream>>>(hseq, Ud_w, Ud_b, vd_w, lbuf);
    final_kernel<<<512, 512, 0, stream>>>(lbuf, hseq, out_w, out_b, out);
}

// Round 9
// 3877.773 us; speedup vs baseline: 1.6315x; 1.0306x over previous
//
#include <hip/hip_runtime.h>
#include <math.h>

// Problem dims
#define T_ 128
#define B_ 512
#define N_ 256
#define M_ 512
#define G_ 2048   // 4*M
#define NBLK 256  // 8 groups x 32 blocks, 1 block/CU, 512 threads = 8 waves/CU
#define GSZ 32    // blocks per group
#define KC_ 24    // K chunks of 32 (768 total: 256 x-tilde + 512 h)

typedef unsigned long long ull;
typedef __attribute__((ext_vector_type(8))) _Float16 half8v;
typedef __attribute__((ext_vector_type(4))) float float4v;

// ---------------------------------------------------------------------------
// Device-coherent access, relaxed: cross-XCD safe
// ---------------------------------------------------------------------------
__device__ __forceinline__ float ld_dev(const float* p) {
    return __hip_atomic_load(const_cast<float*>(p), __ATOMIC_RELAXED,
                             __HIP_MEMORY_SCOPE_AGENT);
}
__device__ __forceinline__ void st_dev(float* p, float v) {
    __hip_atomic_store(p, v, __ATOMIC_RELAXED, __HIP_MEMORY_SCOPE_AGENT);
}
__device__ __forceinline__ ull ld_dev64(const ull* p) {
    return __hip_atomic_load(const_cast<ull*>(p), __ATOMIC_RELAXED,
                             __HIP_MEMORY_SCOPE_AGENT);
}
__device__ __forceinline__ void st_dev64(ull* p, ull v) {
    __hip_atomic_store(p, v, __ATOMIC_RELAXED, __HIP_MEMORY_SCOPE_AGENT);
}

// Fast transcendentals (abs err ~1e-6, threshold 1e-3)
__device__ __forceinline__ float fast_tanh(float x) {
    float e = __expf(2.f * x);
    return 1.f - __fdividef(2.f, e + 1.f);
}
__device__ __forceinline__ float fast_sig(float x) {
    return __fdividef(1.f, 1.f + __expf(-x));
}

// bf16 helpers (RNE) — still used for the ue path
__device__ __forceinline__ unsigned short bf16_rne(float f) {
    unsigned u = __float_as_uint(f);
    return (unsigned short)((u + 0x7FFFu + ((u >> 16) & 1u)) >> 16);
}
// fp16 bits (RNE via hardware cvt)
__device__ __forceinline__ unsigned short f16_bits(float f) {
    union { _Float16 h; unsigned short u; } cv;
    cv.h = (_Float16)f;
    return cv.u;
}
__device__ __forceinline__ ull pack4(const unsigned short* s) {
    return (ull)s[0] | ((ull)s[1] << 16) | ((ull)s[2] << 32) | ((ull)s[3] << 48);
}

// ---------------------------------------------------------------------------
// Group barrier: 32 blocks, relaxed ticket, no L2 flush.
// ---------------------------------------------------------------------------
__device__ __forceinline__ void group_bar(int* gbar, int goal) {
    __syncthreads();
    if (threadIdx.x == 0) {
        asm volatile("s_waitcnt vmcnt(0)" ::: "memory");
        __hip_atomic_fetch_add(gbar, 1, __ATOMIC_RELAXED,
                               __HIP_MEMORY_SCOPE_AGENT);
        while (__hip_atomic_load(gbar, __ATOMIC_RELAXED,
                                 __HIP_MEMORY_SCOPE_AGENT) < goal) {
            __builtin_amdgcn_s_sleep(1);
        }
    }
    __syncthreads();
}

// ---------------------------------------------------------------------------
// Prep: fused bias bg[4m+g] = b_ih[g*512+m] + b_hh[g*512+m]
// ---------------------------------------------------------------------------
__global__ __launch_bounds__(256) void prep_bg(
    const float* __restrict__ bih, const float* __restrict__ bhh,
    float* __restrict__ bg)
{
    int rp = blockIdx.x * 256 + threadIdx.x;
    if (rp < 2048) {
        int m = rp >> 2, g = rp & 3;
        int row = g * 512 + m;
        bg[rp] = bih[row] + bhh[row];
    }
}

// ---------------------------------------------------------------------------
// Prep: Wt fragment-tiled SINGLE-PLANE fp16.
// ---------------------------------------------------------------------------
__global__ __launch_bounds__(256) void prep_wt(
    const float* __restrict__ Wih, const float* __restrict__ Whh,
    uint4* __restrict__ Wt)
{
    int uid = blockIdx.x * 256 + threadIdx.x;   // < 196608
    int ct = uid / (KC_ * 64);
    int rem = uid % (KC_ * 64);
    int kc = rem >> 6, lane = rem & 63;
    int col = ct * 16 + (lane & 15);
    int m = col >> 2, gi = col & 3;
    int grow = gi * 512 + m;
    int quad = lane >> 4;
    union { unsigned short s[8]; uint4 v; } o;
#pragma unroll
    for (int j = 0; j < 8; j++) {
        int k = kc * 32 + quad * 8 + j;
        float v = (k < 256) ? Wih[(size_t)grow * 256 + k]
                            : Whh[(size_t)grow * 512 + (k - 256)];
        o.s[j] = f16_bits(v);
    }
    Wt[uid] = o.v;
}

// ---------------------------------------------------------------------------
// Prep: Wes16 fp16 B-fragments of We for the in-Part-A we-MFMA.
// Wes16[ct][kc][lane]: col s = ct*16+(lane&15), k = kc*32+(lane>>4)*8+j.
// 8 ct x 32 kc x 64 lanes x 16B = 256 KB (replaces 512 KB f32 We_p).
// ---------------------------------------------------------------------------
__global__ __launch_bounds__(256) void prep_wes16(
    const float* __restrict__ We_w, uint4* __restrict__ Wes16)
{
    int uid = blockIdx.x * 256 + threadIdx.x;   // < 16384
    int ct = uid >> 11;
    int kc = (uid >> 6) & 31;
    int lane = uid & 63;
    int s = ct * 16 + (lane & 15);
    int k0 = kc * 32 + (lane >> 4) * 8;
    union { unsigned short s[8]; uint4 v; } o;
#pragma unroll
    for (int j = 0; j < 8; j++)
        o.s[j] = f16_bits(We_w[s * 1024 + k0 + j]);
    Wes16[uid] = o.v;
}

// ---------------------------------------------------------------------------
// Precompute (Ue_x + Ue_b) * 2, packed bf16 s-pairs.
// ---------------------------------------------------------------------------
__global__ __launch_bounds__(256) void ue_pre(
    const float* __restrict__ x, const float* __restrict__ Ue_w,
    const float* __restrict__ Ue_b, unsigned* __restrict__ ue_pk)
{
    const int b = blockIdx.y;
    const int s0 = blockIdx.x * 32;
    const int n = threadIdx.x;
    __shared__ float xs[32][256];
    __shared__ float uws[32][32];

    float acc[32];
#pragma unroll
    for (int i = 0; i < 32; i++) acc[i] = 0.f;

#pragma unroll 1
    for (int tc = 0; tc < 4; tc++) {
        __syncthreads();
#pragma unroll
        for (int tt = 0; tt < 32; tt++)
            xs[tt][n] = x[(size_t)(tc * 32 + tt) * (B_ * N_) + b * N_ + n];
#pragma unroll
        for (int q = 0; q < 4; q++) {
            int e = q * 256 + n;
            int s = e >> 5, tt = e & 31;
            uws[s][tt] = Ue_w[(s0 + s) * T_ + tc * 32 + tt];
        }
        __syncthreads();
        float xr[32];
#pragma unroll
        for (int tt = 0; tt < 32; tt++) xr[tt] = xs[tt][n];
#pragma unroll
        for (int s = 0; s < 32; s++) {
            float a = acc[s];
#pragma unroll
            for (int tt = 0; tt < 32; tt++) a += xr[tt] * uws[s][tt];
            acc[s] = a;
        }
    }
#pragma unroll
    for (int i = 0; i < 16; i++) {
        float v0 = (acc[2 * i] + Ue_b[s0 + 2 * i]) * 2.0f;
        float v1 = (acc[2 * i + 1] + Ue_b[s0 + 2 * i + 1]) * 2.0f;
        unsigned pk = (unsigned)bf16_rne(v0) | ((unsigned)bf16_rne(v1) << 16);
        ue_pk[((size_t)b * 64 + (s0 >> 1) + i) * 256 + n] = pk;
    }
}

// ---------------------------------------------------------------------------
// Persistent scan. R8 base (fp16 gates GEMM, frozen structure) + this round:
// the we-GEMM runs on the MFMA pipe (idle during Part A) instead of 512
// VALU FMAs/thread: wave w computes we[2 batches][s = w*16..w*16+15] via 32
// sequential mfma_f32_16x16x32_f16 (K=1024), A = fp16 mirror of hc in LDS
// (converted during staging, free), B = Wes16 fragments (256 KB L2 stream,
// half of the old f32 We_p). Deletes wepart buffers + one reduce barrier.
// Fragment mappings identical to the validated Part C (A row=lane&15,
// k=(lane>>4)*8+j; D col=lane&15, row=quad*4+reg -> batches in acc[0],[1]
// of lanes 0-15). Rows 2-15 are garbage duplicates, outputs discarded.
// ---------------------------------------------------------------------------
__global__ __launch_bounds__(512, 1) void scan_persist(
    const float* __restrict__ x, const float* __restrict__ h0,
    const half8v* __restrict__ Wes16, const float* __restrict__ We_b,
    const float* __restrict__ ve_w, const unsigned* __restrict__ ue_pk,
    const half8v* __restrict__ Wt,
    const float* __restrict__ bg,
    float* __restrict__ cbuf, float* __restrict__ hseq,
    ull* __restrict__ At, int* bar)
{
    const int tid = threadIdx.x;
    const int blk = blockIdx.x;
    const int g = blk >> 5;          // group 0..7
    const int sg = blk & 31;         // slot in group
    int* gbar = bar + g * 32;

    __shared__ __align__(16) float hcA[1024];
    __shared__ __align__(16) float hcB[1024];
    __shared__ __align__(16) unsigned short hc16[2][1024];  // fp16 hc mirror
    __shared__ __align__(16) float wv[2][256];   // [half][s*2+{2*we, 2*ve}]
    __shared__ float red[16];
    __shared__ float xs[2][256];
    __shared__ float gates_s[64][65];

    // part A ids
    const int bA = g * 64 + sg * 2;
    const int bB = bA + 1;
    const int half = tid >> 8;       // batch half (wave-uniform)
    const int tt = tid & 255;        // n
    // part C ids
    const int lane = tid & 63;
    const int w = tid >> 6;          // wave 0..7
    const int rtC = g * 4 + (w & 3);
    const int ctA = sg * 4 + (w >> 2) * 2;
    const int ctB = ctA + 1;
    const int quad = lane >> 4;
    // cell ids (loop-invariant)
    const int mi_c = tid & 15;
    const int b_l0 = tid >> 4;                   // 0..31
    const int cidx0 = (g * 64 + b_l0) * M_ + sg * 16 + mi_c;
    const int cidx1 = cidx0 + 32 * M_;

    if (tid < 128) {
        float v = 2.0f * ve_w[tid];  // pre-doubled: e -= (2*ve) * rcp(E+1)
        wv[0][tid * 2 + 1] = v;
        wv[1][tid * 2 + 1] = v;
    }

    // loop-invariant fused biases for this thread's cells
    const float bgi = bg[sg * 64 + mi_c * 4 + 0];
    const float bgf = bg[sg * 64 + mi_c * 4 + 1];
    const float bgc = bg[sg * 64 + mi_c * 4 + 2];
    const float bgo = bg[sg * 64 + mi_c * 4 + 3];

    // we-MFMA lane constants: A row = lane&15 (row&1 picks the batch;
    // rows 2-15 duplicate), k-octet = lane>>4
    const unsigned short* hsrc = &hc16[lane & 1][0];   // (lane&15)&1 == lane&1
    const int koct = lane >> 4;

    // ---- one-time: load this thread's ue slice (all 128 s) into VGPRs ----
    unsigned ureg[64];
    {
        const unsigned* up = ue_pk + ((size_t)(bA + half) * 64) * 256 + tt;
#pragma unroll
        for (int i = 0; i < 64; i++) ureg[i] = up[(size_t)i * 256];
    }

#pragma unroll 1
    for (int t = 0; t < T_; t++) {
        const float* hprev = t ? (hseq + (size_t)(t - 1) * (B_ * M_)) : h0;

        // ---------------- Part A ----------------
        {
            float a0 = ld_dev(hprev + bA * M_ + tid);
            float a1 = ld_dev(cbuf + bA * M_ + tid);
            float b0 = ld_dev(hprev + bB * M_ + tid);
            float b1 = ld_dev(cbuf + bB * M_ + tid);
            hcA[tid] = a0;       hcA[512 + tid] = a1;
            hcB[tid] = b0;       hcB[512 + tid] = b1;
            hc16[0][tid] = f16_bits(a0);  hc16[0][512 + tid] = f16_bits(a1);
            hc16[1][tid] = f16_bits(b0);  hc16[1][512 + tid] = f16_bits(b1);
            // hoist x read above the attention loop (independent)
            float xv = x[(size_t)t * (B_ * N_) + (bA + half) * N_ + tt];
            __syncthreads();

            // ---- emit h-region At (kc 8..23) EARLY: only needs h(t-1);
            //      stores drain under we-MFMA + attention compute ----
            if (tid < 128) {
                int rowsel = tid >> 6;
                int q2 = tid & 63;
                int kc = 8 + (q2 >> 2), qd = q2 & 3;
                const float* hcX = rowsel ? hcB : hcA;
                int mb = (kc - 8) * 32 + qd * 8;
                float v[8];
#pragma unroll
                for (int j = 0; j < 8; j++) v[j] = hcX[mb + j];
                int b2 = bA + rowsel;
                int rt = b2 >> 4;
                int ln = qd * 16 + (b2 & 15);
                size_t uidx = ((size_t)(rt * KC_ + kc) * 64 + ln) * 2;
                unsigned short fh[8];
#pragma unroll
                for (int j = 0; j < 8; j++) fh[j] = f16_bits(v[j]);
                st_dev64(At + uidx,     pack4(fh));
                st_dev64(At + uidx + 1, pack4(fh + 4));
            }

            // we-MFMA: wave w owns s = w*16..w*16+15; K=1024 over 32 kc,
            // rolled 1-ahead (A from LDS fp16 mirror, B from Wes16 L2 stream)
            {
                float4v accw = {0.f, 0.f, 0.f, 0.f};
                half8v pa = *(const half8v*)&hsrc[koct * 8];
                half8v pb = Wes16[(w * 32 + 0) * 64 + lane];
#pragma unroll 1
                for (int kc = 0; kc < 32; kc++) {
                    half8v av = pa, bv = pb;
                    if (kc + 1 < 32) {
                        pa = *(const half8v*)&hsrc[(kc + 1) * 32 + koct * 8];
                        pb = Wes16[(w * 32 + kc + 1) * 64 + lane];
                    }
                    accw = __builtin_amdgcn_mfma_f32_16x16x32_f16(av, bv, accw, 0, 0, 0);
                }
                // D: col=lane&15, row=quad*4+reg -> rows 0,1 = batches A,B
                if (lane < 16) {
                    int s = w * 16 + lane;
                    float wb = We_b[s];
                    wv[0][2 * s] = (accw[0] + wb) * 2.0f;
                    wv[1][2 * s] = (accw[1] + wb) * 2.0f;
                }
            }
            __syncthreads();

            // attention: accumulate -2ve*rcp(exp(2z)+1) (Sum(ve) dropped)
            float e = 0.f;
#pragma unroll
            for (int i = 0; i < 64; i++) {
                unsigned u = ureg[i];
                float4 q = *(const float4*)&wv[half][i * 4];
                float z0 = q.x + __uint_as_float(u << 16);
                float z1 = q.z + __uint_as_float(u & 0xFFFF0000u);
                float r0 = __builtin_amdgcn_rcpf(__expf(z0) + 1.f);
                float r1 = __builtin_amdgcn_rcpf(__expf(z1) + 1.f);
                e = fmaf(-q.y, r0, e);
                e = fmaf(-q.w, r1, e);
            }

            // softmax over n (256 = 4 waves per half): shfl reduce + combine
            float m = e;
#pragma unroll
            for (int off = 32; off >= 1; off >>= 1)
                m = fmaxf(m, __shfl_xor(m, off));
            if (lane == 0) red[w] = m;
            __syncthreads();
            float mx = fmaxf(fmaxf(red[half * 4 + 0], red[half * 4 + 1]),
                             fmaxf(red[half * 4 + 2], red[half * 4 + 3]));
            float ex = __expf(e - mx);
            float sm = ex;
#pragma unroll
            for (int off = 32; off >= 1; off >>= 1)
                sm += __shfl_xor(sm, off);
            if (lane == 0) red[8 + w] = sm;
            __syncthreads();
            float denom = red[8 + half * 4 + 0] + red[8 + half * 4 + 1]
                        + red[8 + half * 4 + 2] + red[8 + half * 4 + 3];
            float alpha = __fdividef(ex, denom);
            xs[half][tt] = alpha * xv;
            __syncthreads();

            // ---- emit x~ region At (kc 0..7) ----
            if (tid >= 128 && tid < 192) {
                int u2 = tid - 128;
                int rowsel = u2 >> 5;
                int q2 = u2 & 31;
                int kc = q2 >> 2, qd = q2 & 3;
                int nb = kc * 32 + qd * 8;
                float v[8];
#pragma unroll
                for (int j = 0; j < 8; j++) v[j] = xs[rowsel][nb + j];
                int b2 = bA + rowsel;
                int rt = b2 >> 4;
                int ln = qd * 16 + (b2 & 15);
                size_t uidx = ((size_t)(rt * KC_ + kc) * 64 + ln) * 2;
                unsigned short fh[8];
#pragma unroll
                for (int j = 0; j < 8; j++) fh[j] = f16_bits(v[j]);
                st_dev64(At + uidx,     pack4(fh));
                st_dev64(At + uidx + 1, pack4(fh + 4));
            }
        }
        group_bar(gbar, (t * 2 + 1) * GSZ);

        // -------- Part C: fp16 gates GEMM (R8 structure, FROZEN) + cell -----
        {
            // prefetch this thread's cell state early (same-thread RAW,
            // relaxed is sufficient); hides latency under the GEMM
            float cold0 = ld_dev(&cbuf[cidx0]);
            float cold1 = ld_dev(&cbuf[cidx1]);

            float4v acc0 = {0.f, 0.f, 0.f, 0.f};
            float4v acc1 = {0.f, 0.f, 0.f, 0.f};

            size_t aidx = ((size_t)(rtC * KC_ + 0) * 64 + lane) * 2;
            ull pa0 = ld_dev64(At + aidx), pa1 = ld_dev64(At + aidx + 1);
            half8v pw0 = Wt[(ctA * KC_ + 0) * 64 + lane];
            half8v pw1 = Wt[(ctB * KC_ + 0) * 64 + lane];

#pragma unroll 1
            for (int kc = 0; kc < KC_; kc++) {
                ull a0 = pa0, a1 = pa1;
                half8v w0 = pw0, w1 = pw1;
                if (kc + 1 < KC_) {
                    size_t ai = ((size_t)(rtC * KC_ + kc + 1) * 64 + lane) * 2;
                    pa0 = ld_dev64(At + ai); pa1 = ld_dev64(At + ai + 1);
                    pw0 = Wt[(ctA * KC_ + kc + 1) * 64 + lane];
                    pw1 = Wt[(ctB * KC_ + kc + 1) * 64 + lane];
                }
                union { ull u[2]; half8v h; } av;
                av.u[0] = a0; av.u[1] = a1;
                acc0 = __builtin_amdgcn_mfma_f32_16x16x32_f16(av.h, w0, acc0, 0, 0, 0);
                acc1 = __builtin_amdgcn_mfma_f32_16x16x32_f16(av.h, w1, acc1, 0, 0, 0);
            }

            // dump C/D (col=lane&15, row=quad*4+reg) into gates tile
            const int r0 = (w & 3) * 16;
            const int c0l = (w >> 2) * 32;
#pragma unroll
            for (int r = 0; r < 4; r++) {
                gates_s[r0 + quad * 4 + r][c0l + (lane & 15)] = acc0[r];
                gates_s[r0 + quad * 4 + r][c0l + 16 + (lane & 15)] = acc1[r];
            }
            __syncthreads();

            // fused cell: this thread's 2 cells (b_l0, mi_c), (b_l0+32, mi_c)
            float* hseq_t = hseq + (size_t)t * (B_ * M_);
            {
                float gi = gates_s[b_l0][mi_c * 4 + 0] + bgi;
                float gf = gates_s[b_l0][mi_c * 4 + 1] + bgf;
                float gc = gates_s[b_l0][mi_c * 4 + 2] + bgc;
                float go = gates_s[b_l0][mi_c * 4 + 3] + bgo;
                float cn = fast_sig(gf) * cold0 + fast_sig(gi) * fast_tanh(gc);
                st_dev(&cbuf[cidx0], cn);
                st_dev(&hseq_t[cidx0], fast_sig(go) * fast_tanh(cn));
            }
            {
                float gi = gates_s[b_l0 + 32][mi_c * 4 + 0] + bgi;
                float gf = gates_s[b_l0 + 32][mi_c * 4 + 1] + bgf;
                float gc = gates_s[b_l0 + 32][mi_c * 4 + 2] + bgc;
                float go = gates_s[b_l0 + 32][mi_c * 4 + 3] + bgo;
                float cn = fast_sig(gf) * cold1 + fast_sig(gi) * fast_tanh(gc);
                st_dev(&cbuf[cidx1], cn);
                st_dev(&hseq_t[cidx1], fast_sig(go) * fast_tanh(cn));
            }
        }
        group_bar(gbar, (t * 2 + 2) * GSZ);
    }
}

// ---------------------------------------------------------------------------
// Post: l[b,t] += sum_m tanh(h_seq@Ud_w^T + Ud_b)*vd_w   (rows=T*B, cols=M)
// ---------------------------------------------------------------------------
__global__ __launch_bounds__(256) void gemm_l(
    const float* __restrict__ A1,
    const float* __restrict__ W1,
    const float* __restrict__ bias1,
    const float* __restrict__ vw, float* __restrict__ lout)
{
    __shared__ float As[16][68];
    __shared__ float Ws[16][68];
    __shared__ float rsum[64];

    const int tid = threadIdx.x;
    const int tx = tid & 15, ty = tid >> 4;
    const int row0 = blockIdx.y * 64;
    const int col0 = blockIdx.x * 64;
    const int li = tid >> 2;
    const int lk4 = (tid & 3) * 4;

    float acc[4][4];
#pragma unroll
    for (int r = 0; r < 4; r++)
#pragma unroll
        for (int cc = 0; cc < 4; cc++) acc[r][cc] = 0.f;

    float4 av = *(const float4*)&A1[(size_t)(row0 + li) * M_ + lk4];
    float4 wvv = *(const float4*)&W1[(size_t)(col0 + li) * M_ + lk4];
#pragma unroll 1
    for (int kk = 0; kk < 512; kk += 16) {
        __syncthreads();
        As[lk4 + 0][li] = av.x; As[lk4 + 1][li] = av.y;
        As[lk4 + 2][li] = av.z; As[lk4 + 3][li] = av.w;
        Ws[lk4 + 0][li] = wvv.x; Ws[lk4 + 1][li] = wvv.y;
        Ws[lk4 + 2][li] = wvv.z; Ws[lk4 + 3][li] = wvv.w;
        __syncthreads();
        if (kk + 16 < 512) {
            av = *(const float4*)&A1[(size_t)(row0 + li) * M_ + kk + 16 + lk4];
            wvv = *(const float4*)&W1[(size_t)(col0 + li) * M_ + kk + 16 + lk4];
        }
#pragma unroll
        for (int k = 0; k < 16; k++) {
            float4 a = *(const float4*)&As[k][ty * 4];
            float4 w2 = *(const float4*)&Ws[k][tx * 4];
            acc[0][0] += a.x * w2.x; acc[0][1] += a.x * w2.y;
            acc[0][2] += a.x * w2.z; acc[0][3] += a.x * w2.w;
            acc[1][0] += a.y * w2.x; acc[1][1] += a.y * w2.y;
            acc[1][2] += a.y * w2.z; acc[1][3] += a.y * w2.w;
            acc[2][0] += a.z * w2.x; acc[2][1] += a.z * w2.y;
            acc[2][2] += a.z * w2.z; acc[2][3] += a.z * w2.w;
            acc[3][0] += a.w * w2.x; acc[3][1] += a.w * w2.y;
            acc[3][2] += a.w * w2.z; acc[3][3] += a.w * w2.w;
        }
    }

    __syncthreads();
    if (tid < 64) rsum[tid] = 0.f;
    __syncthreads();
    float part[4] = {0.f, 0.f, 0.f, 0.f};
#pragma unroll
    for (int r = 0; r < 4; r++)
#pragma unroll
        for (int cc = 0; cc < 4; cc++) {
            int gc = col0 + tx * 4 + cc;
            part[r] += fast_tanh(acc[r][cc] + bias1[gc]) * vw[gc];
        }
#pragma unroll
    for (int r = 0; r < 4; r++)
        atomicAdd(&rsum[ty * 4 + r], part[r]);
    __syncthreads();
    if (tid < 64) {
        int gr = row0 + tid;          // gr = t*512 + b
        int b = gr & 511, t = gr >> 9;
        atomicAdd(&lout[b * 128 + t], rsum[tid]);
    }
}

// ---------------------------------------------------------------------------
// Final: beta = softmax_t(l); ctx = sum_t beta*h_seq; logits = ctx.out_w+out_b
// ---------------------------------------------------------------------------
__global__ __launch_bounds__(512) void final_kernel(
    const float* __restrict__ lbuf, const float* __restrict__ hseq,
    const float* __restrict__ out_w, const float* __restrict__ out_b,
    float* __restrict__ out)
{
    const int b = blockIdx.x;
    const int tid = threadIdx.x;
    __shared__ float beta_s[128];
    __shared__ float red[512];

    float lv = (tid < 128) ? lbuf[b * 128 + tid] : -1e30f;
    red[tid] = lv; __syncthreads();
    for (int off = 256; off >= 1; off >>= 1) {
        if (tid < off) red[tid] = fmaxf(red[tid], red[tid + off]);
        __syncthreads();
    }
    float mx = red[0]; __syncthreads();
    float ex = (tid < 128) ? __expf(lv - mx) : 0.f;
    red[tid] = ex; __syncthreads();
    for (int off = 256; off >= 1; off >>= 1) {
        if (tid < off) red[tid] += red[tid + off];
        __syncthreads();
    }
    float denom = red[0];
    if (tid < 128) {
        float bt = ex / denom;
        beta_s[tid] = bt;
        out[512 + b * 128 + tid] = bt;
    }
    __syncthreads();

    float ctx = 0.f;
#pragma unroll 4
    for (int t = 0; t < 128; t++)
        ctx += beta_s[t] * hseq[(size_t)t * (B_ * M_) + b * M_ + tid];

    red[tid] = ctx * out_w[tid]; __syncthreads();
    for (int off = 256; off >= 1; off >>= 1) {
        if (tid < off) red[tid] += red[tid + off];
        __syncthreads();
    }
    if (tid == 0) out[b] = red[0] + out_b[0];
}

// ---------------------------------------------------------------------------
extern "C" void kernel_launch(void* const* d_in, const int* in_sizes, int n_in,
                              void* d_out, int out_size, void* d_ws, size_t ws_size,
                              hipStream_t stream)
{
    const float* x    = (const float*)d_in[0];
    const float* h0   = (const float*)d_in[1];
    const float* c0   = (const float*)d_in[2];
    const float* Wih  = (const float*)d_in[3];
    const float* Whh  = (const float*)d_in[4];
    const float* b_ih = (const float*)d_in[5];
    const float* b_hh = (const float*)d_in[6];
    const float* We_w = (const float*)d_in[7];
    const float* We_b = (const float*)d_in[8];
    const float* Ue_w = (const float*)d_in[9];
    const float* Ue_b = (const float*)d_in[10];
    const float* ve_w = (const float*)d_in[11];
    const float* Ud_w = (const float*)d_in[13];
    const float* Ud_b = (const float*)d_in[14];
    const float* vd_w = (const float*)d_in[15];
    const float* out_w = (const float*)d_in[17];
    const float* out_b = (const float*)d_in[18];
    float* out = (float*)d_out;

    // workspace layout (float slots). lbuf aliases ue_pk (disjoint lifetimes).
    float* ws    = (float*)d_ws;
    float* ue_pk = ws;                       //  8,388,608  (B*64*N uints) [scan]
    float* lbuf  = ws;                       //     65,536  (B*T)   [post only]
    float* hseq  = ue_pk + 8388608;          // 33,554,432  (T*B*M)
    float* cbuf  = hseq + 33554432;          //    262,144  (B*M)
    float* Wes16 = cbuf + 262144;            //     65,536  (8ct*32kc*64 fp16x8)
    float* bgv   = Wes16 + 65536;            //      2,048
    float* At_f  = bgv + 2048;               //    196,608  (32*24*64*8 fp16)
    float* Wt_f  = At_f + 196608;            //    786,432  (128*24*64*8 fp16)
    int*   bar   = (int*)(Wt_f + 786432);    //   8*32 ints

    hipMemcpyAsync(cbuf, c0, (size_t)B_ * M_ * 4, hipMemcpyDeviceToDevice, stream);
    hipMemsetAsync(bar, 0, 8 * 32 * 4, stream);

    prep_bg<<<8, 256, 0, stream>>>(b_ih, b_hh, bgv);
    prep_wt<<<768, 256, 0, stream>>>(Wih, Whh, (uint4*)Wt_f);
    prep_wes16<<<64, 256, 0, stream>>>(We_w, (uint4*)Wes16);
    ue_pre<<<dim3(4, 512), 256, 0, stream>>>(x, Ue_w, Ue_b, (unsigned*)ue_pk);

    scan_persist<<<NBLK, 512, 0, stream>>>(
        x, h0, (const half8v*)Wes16, We_b, ve_w, (const unsigned*)ue_pk,
        (const half8v*)Wt_f, bgv,
        cbuf, hseq, (ull*)At_f, bar);

    hipMemsetAsync(lbuf, 0, (size_t)B_ * T_ * 4, stream);
    gemm_l<<<dim3(8, 1024), 256, 0, stream>>>(hseq, Ud_w, Ud_b, vd_w, lbuf);
    final_kernel<<<512, 512, 0, stream>>>(lbuf, hseq, out_w, out_b, out);
}